// Round 8
// baseline (519.901 us; speedup 1.0000x reference)
//
#include <hip/hip_runtime.h>

// LowRankGDN: out[n,c,p] = x[n,c,p] * rsqrt( beta_r[c] + sum_r A_r[c,r] * T[n,r,p] )
//   T[n,r,p] = sum_c A_r[c,r] * x[n,c,p]^2
// Shapes: x [8,192,256,256] f32, beta [192], A [192,8]. Output f32, same shape.
//
// R8: isolate DRAM chunk-width (256B -> 512B per wave-instr) WITHOUT the
// R5 confounds. 1024 thr = 16 channel-slices x 64 lanes, CPT=12, float2
// (2 px/thread). xr 24 + T 16 + temps ~55 VGPR; launch_bounds(1024,8)
// caps VGPR<=64 -> 2 blocks/CU = 32 waves/CU (100% cap). LDS 71 KB -> 2
// blocks/CU fits. x register-resident (minimal 805 MB traffic, the
// measured-best structure: R4=167us vs L2/L3-reread R2/R6=206-211us).
// NT stores only (NT loads + XCD swizzle measured neutral in R7).

#define N_IMG 8
#define C_CH 192
#define R_RK 8
#define HW 65536              // 256*256
#define PXB 128               // pixels per block (64 lanes * 2)
#define CSLICES 16
#define CPT (C_CH / CSLICES)  // 12 channels per thread
#define NTHR 1024
#define BLOCKS_PER_IMG (HW / PXB)     // 512
#define NBLK (N_IMG * BLOCKS_PER_IMG) // 4096

#define PEDESTAL_F 1.4551915228366852e-11f    // 2^-36
#define BOUND_A_F 3.814697265625e-06f         // 2^-18 = sqrt(pedestal)
#define BOUND_BETA_F 1.0000072759311364e-03f  // sqrt(1e-6 + 2^-36)

typedef float v2 __attribute__((ext_vector_type(2)));

__global__ __launch_bounds__(NTHR, 8) void lrgdn_kernel(
    const float* __restrict__ x,
    const float* __restrict__ beta,
    const float* __restrict__ A,
    float* __restrict__ out)
{
    __shared__ float sA[C_CH][R_RK];          // reparametrized A (6 KB)
    __shared__ float sB[C_CH];                // reparametrized beta
    __shared__ v2 sT[CSLICES][R_RK][64];      // partial T (64 KB)

    const int tid = threadIdx.x;

    // Reparametrize params into LDS (tiny)
    for (int i = tid; i < C_CH * R_RK; i += NTHR) {
        float a = fmaxf(A[i], BOUND_A_F);
        sA[i >> 3][i & 7] = a * a - PEDESTAL_F;
    }
    if (tid < C_CH) {
        float b = fmaxf(beta[tid], BOUND_BETA_F);
        sB[tid] = b * b - PEDESTAL_F;
    }
    __syncthreads();

    const int blk  = blockIdx.x;
    const int n    = blk / BLOCKS_PER_IMG;
    const int p0   = (blk % BLOCKS_PER_IMG) * PXB;
    const int lane = tid & 63;
    const int cs   = tid >> 6;          // channel slice 0..15 (uniform per wave)
    const int c0   = cs * CPT;

    const float* xn = x   + (size_t)n * (C_CH * HW) + p0 + (size_t)c0 * HW + 2 * lane;
    float*       on = out + (size_t)n * (C_CH * HW) + p0 + (size_t)c0 * HW + 2 * lane;

    // ---- load this thread's 12 channels x 2 px into registers ----
    v2 xr[CPT];
#pragma unroll
    for (int i = 0; i < CPT; ++i) {
        xr[i] = *reinterpret_cast<const v2*>(xn + (size_t)i * HW);
    }

    // ---- accumulate partial T ----
    v2 T[R_RK];
#pragma unroll
    for (int r = 0; r < R_RK; ++r) T[r] = (v2)0.f;

#pragma unroll
    for (int i = 0; i < CPT; ++i) {
        v2 s = xr[i] * xr[i];
#pragma unroll
        for (int r = 0; r < R_RK; ++r) {
            T[r] += s * sA[c0 + i][r];     // uniform LDS addr -> broadcast; fma
        }
    }

    // ---- cross-slice reduce via LDS (one barrier) ----
#pragma unroll
    for (int r = 0; r < R_RK; ++r) {
        sT[cs][r][lane] = T[r];            // b64 writes, lanes consecutive: conflict-free
    }
    __syncthreads();

#pragma unroll
    for (int r = 0; r < R_RK; ++r) {
        v2 acc0 = sT[0][r][lane] + sT[1][r][lane];
        v2 acc1 = sT[2][r][lane] + sT[3][r][lane];
        v2 acc2 = sT[4][r][lane] + sT[5][r][lane];
        v2 acc3 = sT[6][r][lane] + sT[7][r][lane];
        v2 acc4 = sT[8][r][lane] + sT[9][r][lane];
        v2 acc5 = sT[10][r][lane] + sT[11][r][lane];
        v2 acc6 = sT[12][r][lane] + sT[13][r][lane];
        v2 acc7 = sT[14][r][lane] + sT[15][r][lane];
        T[r] = ((acc0 + acc1) + (acc2 + acc3)) + ((acc4 + acc5) + (acc6 + acc7));
    }

    // ---- epilogue: denom + rsqrt + store (nontemporal), from registers ----
#pragma unroll
    for (int i = 0; i < CPT; ++i) {
        int c = c0 + i;
        v2 d;
        d.x = sB[c];
        d.y = d.x;
#pragma unroll
        for (int r = 0; r < R_RK; ++r) {
            d += sA[c][r] * T[r];
        }
        v2 o;
        o.x = xr[i].x * __builtin_amdgcn_rsqf(d.x);
        o.y = xr[i].y * __builtin_amdgcn_rsqf(d.y);
        __builtin_nontemporal_store(o, reinterpret_cast<v2*>(on + (size_t)i * HW));
    }
}

extern "C" void kernel_launch(void* const* d_in, const int* in_sizes, int n_in,
                              void* d_out, int out_size, void* d_ws, size_t ws_size,
                              hipStream_t stream) {
    const float* x    = (const float*)d_in[0];
    const float* beta = (const float*)d_in[1];
    const float* A    = (const float*)d_in[2];
    float* out = (float*)d_out;

    dim3 grid(NBLK);     // 4096 blocks
    dim3 block(NTHR);    // 1024
    hipLaunchKernelGGL(lrgdn_kernel, grid, block, 0, stream, x, beta, A, out);
}

// Round 9
// 192.177 us; speedup vs baseline: 2.7053x; 2.7053x over previous
//
#include <hip/hip_runtime.h>

// LowRankGDN: out[n,c,p] = x[n,c,p] * rsqrt( beta_r[c] + sum_r A_r[c,r] * T[n,r,p] )
//   T[n,r,p] = sum_c A_r[c,r] * x[n,c,p]^2
// Shapes: x [8,192,256,256] f32, beta [192], A [192,8]. Output f32, same shape.
//
// R9: R8's geometry (1024 thr = 16 slices x 64 lanes, CPT=12, float2 =
// 512B/wave-instr chunks) but launch_bounds(1024,4): VGPR cap 128 instead
// of the (1024,8) cap of 64 that forced VGPR=32 + ~1.1 GB scratch spill
// traffic in R8 (WRITE 1.59 GB, 520us). Natural VGPR ~52 <= 64, so the HW
// scheduler can still reach 8 waves/EU = 2 blocks/CU = 100% occupancy; the
// looser bound only removes the forced spill. This isolates chunk width
// (256B->512B) at equal occupancy vs R4 (167us).

#define N_IMG 8
#define C_CH 192
#define R_RK 8
#define HW 65536              // 256*256
#define PXB 128               // pixels per block (64 lanes * 2)
#define CSLICES 16
#define CPT (C_CH / CSLICES)  // 12 channels per thread
#define NTHR 1024
#define BLOCKS_PER_IMG (HW / PXB)     // 512
#define NBLK (N_IMG * BLOCKS_PER_IMG) // 4096

#define PEDESTAL_F 1.4551915228366852e-11f    // 2^-36
#define BOUND_A_F 3.814697265625e-06f         // 2^-18 = sqrt(pedestal)
#define BOUND_BETA_F 1.0000072759311364e-03f  // sqrt(1e-6 + 2^-36)

typedef float v2 __attribute__((ext_vector_type(2)));

__global__ __launch_bounds__(NTHR, 4) void lrgdn_kernel(
    const float* __restrict__ x,
    const float* __restrict__ beta,
    const float* __restrict__ A,
    float* __restrict__ out)
{
    __shared__ float sA[C_CH][R_RK];          // reparametrized A (6 KB)
    __shared__ float sB[C_CH];                // reparametrized beta
    __shared__ v2 sT[CSLICES][R_RK][64];      // partial T (64 KB)

    const int tid = threadIdx.x;

    // Reparametrize params into LDS (tiny)
    for (int i = tid; i < C_CH * R_RK; i += NTHR) {
        float a = fmaxf(A[i], BOUND_A_F);
        sA[i >> 3][i & 7] = a * a - PEDESTAL_F;
    }
    if (tid < C_CH) {
        float b = fmaxf(beta[tid], BOUND_BETA_F);
        sB[tid] = b * b - PEDESTAL_F;
    }
    __syncthreads();

    const int blk  = blockIdx.x;
    const int n    = blk / BLOCKS_PER_IMG;
    const int p0   = (blk % BLOCKS_PER_IMG) * PXB;
    const int lane = tid & 63;
    const int cs   = tid >> 6;          // channel slice 0..15 (uniform per wave)
    const int c0   = cs * CPT;

    const float* xn = x   + (size_t)n * (C_CH * HW) + p0 + (size_t)c0 * HW + 2 * lane;
    float*       on = out + (size_t)n * (C_CH * HW) + p0 + (size_t)c0 * HW + 2 * lane;

    // ---- load this thread's 12 channels x 2 px into registers ----
    v2 xr[CPT];
#pragma unroll
    for (int i = 0; i < CPT; ++i) {
        xr[i] = *reinterpret_cast<const v2*>(xn + (size_t)i * HW);
    }

    // ---- accumulate partial T ----
    v2 T[R_RK];
#pragma unroll
    for (int r = 0; r < R_RK; ++r) T[r] = (v2)0.f;

#pragma unroll
    for (int i = 0; i < CPT; ++i) {
        v2 s = xr[i] * xr[i];
#pragma unroll
        for (int r = 0; r < R_RK; ++r) {
            T[r] += s * sA[c0 + i][r];     // uniform LDS addr -> broadcast; fma
        }
    }

    // ---- cross-slice reduce via LDS (one barrier) ----
#pragma unroll
    for (int r = 0; r < R_RK; ++r) {
        sT[cs][r][lane] = T[r];            // b64 writes, lanes consecutive: 2-way free
    }
    __syncthreads();

#pragma unroll
    for (int r = 0; r < R_RK; ++r) {
        v2 acc0 = sT[0][r][lane] + sT[1][r][lane];
        v2 acc1 = sT[2][r][lane] + sT[3][r][lane];
        v2 acc2 = sT[4][r][lane] + sT[5][r][lane];
        v2 acc3 = sT[6][r][lane] + sT[7][r][lane];
        v2 acc4 = sT[8][r][lane] + sT[9][r][lane];
        v2 acc5 = sT[10][r][lane] + sT[11][r][lane];
        v2 acc6 = sT[12][r][lane] + sT[13][r][lane];
        v2 acc7 = sT[14][r][lane] + sT[15][r][lane];
        T[r] = ((acc0 + acc1) + (acc2 + acc3)) + ((acc4 + acc5) + (acc6 + acc7));
    }

    // ---- epilogue: denom + rsqrt + store (nontemporal), from registers ----
#pragma unroll
    for (int i = 0; i < CPT; ++i) {
        int c = c0 + i;
        v2 d;
        d.x = sB[c];
        d.y = d.x;
#pragma unroll
        for (int r = 0; r < R_RK; ++r) {
            d += sA[c][r] * T[r];
        }
        v2 o;
        o.x = xr[i].x * __builtin_amdgcn_rsqf(d.x);
        o.y = xr[i].y * __builtin_amdgcn_rsqf(d.y);
        __builtin_nontemporal_store(o, reinterpret_cast<v2*>(on + (size_t)i * HW));
    }
}

extern "C" void kernel_launch(void* const* d_in, const int* in_sizes, int n_in,
                              void* d_out, int out_size, void* d_ws, size_t ws_size,
                              hipStream_t stream) {
    const float* x    = (const float*)d_in[0];
    const float* beta = (const float*)d_in[1];
    const float* A    = (const float*)d_in[2];
    float* out = (float*)d_out;

    dim3 grid(NBLK);     // 4096 blocks
    dim3 block(NTHR);    // 1024
    hipLaunchKernelGGL(lrgdn_kernel, grid, block, 0, stream, x, beta, A, out);
}

// Round 10
// 167.277 us; speedup vs baseline: 3.1080x; 1.1489x over previous
//
#include <hip/hip_runtime.h>

// LowRankGDN: out[n,c,p] = x[n,c,p] * rsqrt( beta_r[c] + sum_r A_r[c,r] * T[n,r,p] )
//   T[n,r,p] = sum_c A_r[c,r] * x[n,c,p]^2
// Shapes: x [8,192,256,256] f32, beta [192], A [192,8]. Output f32, same shape.
//
// R10 = R4 restored (measured best: 167 us). Final structure after 9 rounds:
// - x register-resident -> minimal fabric traffic (805 MB one read + one
//   write). Alternatives measured worse: L3 reread (R2/R6: 206-211us),
//   float2/float4 widths (R5/R9: 188/192us), forced-occupancy (R8: spills).
// - 512 thr = 8 channel-slices x 64 px; CPT=24 scalar dwords (256 B/wave
//   granule is forced by covering 192ch x 64px in registers).
// - launch_bounds(512,8) -> VGPR<=64 -> up to 32 waves/CU.
// - one LDS reduce barrier; NT stores (NT loads / XCD swizzle were neutral, R7).
// Effective 4.8 TB/s on minimal traffic = ~76% of copy ceiling; limiter is
// the NCHW channel-stride DRAM granule, structural to this op.

#define N_IMG 8
#define C_CH 192
#define R_RK 8
#define HW 65536              // 256*256
#define PX_PER_BLOCK 64
#define CSLICES 8
#define CPT (C_CH / CSLICES)  // 24 channels per thread
#define NTHR (PX_PER_BLOCK * CSLICES)         // 512
#define BLOCKS_PER_IMG (HW / PX_PER_BLOCK)    // 1024

#define PEDESTAL_F 1.4551915228366852e-11f    // 2^-36
#define BOUND_A_F 3.814697265625e-06f         // 2^-18 = sqrt(pedestal)
#define BOUND_BETA_F 1.0000072759311364e-03f  // sqrt(1e-6 + 2^-36)

__global__ __launch_bounds__(NTHR, 8) void lrgdn_kernel(
    const float* __restrict__ x,
    const float* __restrict__ beta,
    const float* __restrict__ A,
    float* __restrict__ out)
{
    __shared__ float sA[C_CH][R_RK];                   // reparametrized A (6 KB)
    __shared__ float sB[C_CH];                         // reparametrized beta
    __shared__ float sT[CSLICES][R_RK][PX_PER_BLOCK];  // partial T (16 KB)

    const int tid = threadIdx.x;

    // Reparametrize params into LDS (tiny)
    for (int i = tid; i < C_CH * R_RK; i += NTHR) {
        float a = A[i];
        a = fmaxf(a, BOUND_A_F);
        sA[i / R_RK][i % R_RK] = a * a - PEDESTAL_F;
    }
    for (int i = tid; i < C_CH; i += NTHR) {
        float b = fmaxf(beta[i], BOUND_BETA_F);
        sB[i] = b * b - PEDESTAL_F;
    }
    __syncthreads();

    const int blk = blockIdx.x;
    const int n  = blk / BLOCKS_PER_IMG;
    const int p0 = (blk % BLOCKS_PER_IMG) * PX_PER_BLOCK;

    const int px = tid & 63;        // wave = 64 consecutive pixels -> coalesced
    const int cs = tid >> 6;        // channel slice (uniform per wave)
    const int c0 = cs * CPT;

    const float* xn = x   + n * (C_CH * HW) + p0 + px + c0 * HW;
    float*       on = out + n * (C_CH * HW) + p0 + px + c0 * HW;

    // ---- load this thread's 24 channels into registers, accumulate T ----
    float xr[CPT];
    float T[R_RK];
#pragma unroll
    for (int r = 0; r < R_RK; ++r) T[r] = 0.f;

#pragma unroll
    for (int i = 0; i < CPT; ++i) {
        xr[i] = xn[i * HW];
    }
#pragma unroll
    for (int i = 0; i < CPT; ++i) {
        float v = xr[i];
        float s = v * v;
#pragma unroll
        for (int r = 0; r < R_RK; ++r) {
            T[r] = fmaf(s, sA[c0 + i][r], T[r]);   // uniform LDS addr -> broadcast
        }
    }

    // ---- cross-slice reduce of T via LDS ----
#pragma unroll
    for (int r = 0; r < R_RK; ++r) {
        sT[cs][r][px] = T[r];       // lanes write consecutive px -> conflict-free
    }
    __syncthreads();

#pragma unroll
    for (int r = 0; r < R_RK; ++r) {
        float t01 = sT[0][r][px] + sT[1][r][px];
        float t23 = sT[2][r][px] + sT[3][r][px];
        float t45 = sT[4][r][px] + sT[5][r][px];
        float t67 = sT[6][r][px] + sT[7][r][px];
        T[r] = (t01 + t23) + (t45 + t67);
    }

    // ---- epilogue: denom + rsqrt + store, all from registers ----
#pragma unroll
    for (int i = 0; i < CPT; ++i) {
        int c = c0 + i;
        float d = sB[c];
#pragma unroll
        for (int r = 0; r < R_RK; ++r) {
            d = fmaf(sA[c][r], T[r], d);
        }
        float o = xr[i] * __builtin_amdgcn_rsqf(d);
        __builtin_nontemporal_store(o, on + i * HW);
    }
}

extern "C" void kernel_launch(void* const* d_in, const int* in_sizes, int n_in,
                              void* d_out, int out_size, void* d_ws, size_t ws_size,
                              hipStream_t stream) {
    const float* x    = (const float*)d_in[0];
    const float* beta = (const float*)d_in[1];
    const float* A    = (const float*)d_in[2];
    float* out = (float*)d_out;

    dim3 grid(N_IMG * BLOCKS_PER_IMG);   // 8192 blocks
    dim3 block(NTHR);                    // 512
    hipLaunchKernelGGL(lrgdn_kernel, grid, block, 0, stream, x, beta, A, out);
}